// Round 6
// baseline (94.236 us; speedup 1.0000x reference)
//
#include <hip/hip_runtime.h>

// MFMA-batched overlapped-chunk HMM forward filter + LDS-staged stores.
// R11: R9 measured 18.8us kernel vs ~11us store roofline. Theory: stores are
// 64B segments (16 per instr, 2KB apart) -> 2x L2 line-transactions/byte
// (and possible partial-line write-allocate fetches); effective write BW
// ~3.4 TB/s == 66MB/18.8us. Fix: wave-private LDS staging of 4-step tiles,
// flushed as 4x256B full-line segments per store instr; ft staged across the
// whole chunk and flushed as 2KB contiguous per wave. Arithmetic identical
// to R9 (3-MFMA split-f16 chain, 1-step-lag normalization) -> absmax same.
#define CHUNK_L 32
#define WARMUP_W 16

typedef _Float16 h16;
typedef _Float16 h16x4 __attribute__((ext_vector_type(4)));
typedef float f32x4 __attribute__((ext_vector_type(4)));

static __device__ __forceinline__ f32x4 mfma16(h16x4 a, h16x4 b, f32x4 c) {
#if __has_builtin(__builtin_amdgcn_mfma_f32_16x16x16f16)
    return __builtin_amdgcn_mfma_f32_16x16x16f16(a, b, c, 0, 0, 0);
#else
    f32x4 d;
    asm volatile("v_mfma_f32_16x16x16_f16 %0, %1, %2, %3\n\ts_nop 7\n\ts_nop 7"
                 : "=v"(d) : "v"(a), "v"(b), "v"(c));
    return d;
#endif
}

__global__ __launch_bounds__(256, 2) void hmm_filter_kernel(
    const float* __restrict__ y,
    const float* __restrict__ logits,
    const float* __restrict__ mu,
    const float* __restrict__ log_sigma,
    float* __restrict__ out,
    int T, int nchunks)
{
    __shared__ float Plds[256];
    __shared__ float Ba[256];
    __shared__ float Bb[256];
    // per-wave staging: [wave][ut 1024 | un 1024] + ft [wave][512]
    __shared__ float SD[4 * 2048 + 4 * 512];

    const int tid = (int)threadIdx.x;
    const int j   = tid & 15;     // column (preamble)
    const int gr  = tid >> 4;     // row (preamble)

    // ---- P = softmax(logits, axis=-1) ----
    float l = logits[tid];
    float m = l;
    #pragma unroll
    for (int s = 1; s < 16; s <<= 1) m = fmaxf(m, __shfl_xor(m, s, 16));
    float e = __expf(l - m);
    float rs = e;
    #pragma unroll
    for (int s = 1; s < 16; s <<= 1) rs += __shfl_xor(rs, s, 16);
    float Pv = e / rs;
    Plds[tid] = Pv;
    Ba[tid]   = Pv;
    __syncthreads();

    // ---- stationary pi: P^(2^10) via renormalized squaring (cold) ----
    float* cur = Ba;
    float* nxt = Bb;
    for (int itq = 0; itq < 10; ++itq) {
        float acc = 0.f;
        #pragma unroll
        for (int k = 0; k < 16; ++k)
            acc += cur[gr * 16 + k] * cur[k * 16 + j];
        float rsum = acc;
        #pragma unroll
        for (int s = 1; s < 16; s <<= 1) rsum += __shfl_xor(rsum, s, 16);
        nxt[tid] = acc / rsum;
        __syncthreads();
        float* tmp = cur; cur = nxt; nxt = tmp;
    }
    // no barriers below this point (early return is safe)

    // ---- lane / wave geometry ----
    const int lane = tid & 63;
    const int col  = lane & 15;          // chunk column  (n)
    const int g4   = (lane >> 4) << 2;   // first of this lane's 4 states
    const int wv   = ((int)blockIdx.x << 2) + (tid >> 6);
    const int cbase = wv << 4;

    const int wbase = (tid >> 6) * 2048;        // stage region (floats)
    const int ftb   = 8192 + (tid >> 6) * 512;  // ft region

    // A = P^T fragments, hi/lo f16 split.  A[m][k]: m=col, k=g4+ee.
    h16x4 Ahi, Alo;
    #pragma unroll
    for (int ee = 0; ee < 4; ++ee) {
        float a = Plds[(g4 + ee) * 16 + col];
        h16 hi = (h16)a;
        Ahi[ee] = hi;
        Alo[ee] = (h16)(a - (float)hi);
    }

    // initial p~ = pi
    h16x4 bhi, blo;
    #pragma unroll
    for (int ee = 0; ee < 4; ++ee) {
        float pv = cur[g4 + ee];
        h16 hi = (h16)pv;
        bhi[ee] = hi;
        blo[ee] = (h16)(pv - (float)hi);
    }

    // emission constants for this lane's 4 states
    float isv[4], nmv[4], lcv[4];
    #pragma unroll
    for (int ee = 0; ee < 4; ++ee) {
        int st = g4 + ee;
        float is = __expf(-log_sigma[st]);
        isv[ee] = is;
        nmv[ee] = -mu[st] * is;
        lcv[ee] = __log2f(0.3989422804014327f * is);
    }
    const float K2 = -0.7213475204444817f;   // -0.5*log2(e)

    if (cbase >= nchunks) return;

    const int chunk = cbase + col;
    const bool isC0 = (chunk == 0);          // warm with g==1 (pi stationary)
    const int Tm4 = T - 4;
    const int TN  = T << 4;

    int tb = chunk * CHUNK_L - WARMUP_W;     // t of current y 4-block

    auto yld = [&](int t) -> float4 {
        int tc = t < 0 ? 0 : (t > Tm4 ? Tm4 : t);
        return *(const float4*)(y + tc);
    };

    float4 c4 = yld(tb);
    float4 n1 = yld(tb + 4);

    float r1 = 1.0f;   // rcp(rowsum of previous step) = 1/c_{t-1}

// Warm-up step: 3 MFMA -> *eg -> f16 split; no outputs.
#define FSTEPW(YT)  do {                                                  \
    f32x4 D = {0.f, 0.f, 0.f, 0.f};                                       \
    D = mfma16(Ahi, bhi, D);                                              \
    D = mfma16(Alo, bhi, D);                                              \
    D = mfma16(Ahi, blo, D);                                              \
    f32x4 eg;                                                             \
    _Pragma("unroll")                                                     \
    for (int ee = 0; ee < 4; ++ee) {                                      \
        float z  = fmaf((YT), isv[ee], nmv[ee]);                          \
        float gg = __builtin_amdgcn_exp2f(fmaf(z * z, K2, lcv[ee]));      \
        eg[ee] = (isC0 ? 1.0f : gg) * r1;                                 \
    }                                                                     \
    f32x4 pg = D * eg;                                                    \
    float sv = (pg.x + pg.y) + (pg.z + pg.w);                             \
    sv += __shfl_xor(sv, 16);                                             \
    sv += __shfl_xor(sv, 32);                                             \
    float rv = __builtin_amdgcn_rcpf(sv);                                 \
    _Pragma("unroll")                                                     \
    for (int ee = 0; ee < 4; ++ee) {                                      \
        h16 hh = (h16)pg[ee];                                             \
        bhi[ee] = hh;                                                     \
        blo[ee] = (h16)(pg[ee] - (float)hh);                              \
    }                                                                     \
    r1 = rv;                                                              \
} while (0)

// Main step: outputs staged to wave-private LDS (TS = 0..3 compile-time).
#define FSTEPS(YT, TS, FDST)  do {                                        \
    f32x4 D = {0.f, 0.f, 0.f, 0.f};                                       \
    D = mfma16(Ahi, bhi, D);                                              \
    D = mfma16(Alo, bhi, D);                                              \
    D = mfma16(Ahi, blo, D);                                              \
    f32x4 eg;                                                             \
    _Pragma("unroll")                                                     \
    for (int ee = 0; ee < 4; ++ee) {                                      \
        float z  = fmaf((YT), isv[ee], nmv[ee]);                          \
        float gg = __builtin_amdgcn_exp2f(fmaf(z * z, K2, lcv[ee]));      \
        eg[ee] = gg * r1;                                                 \
    }                                                                     \
    f32x4 pg = D * eg;                                                    \
    float sv = (pg.x + pg.y) + (pg.z + pg.w);                             \
    sv += __shfl_xor(sv, 16);                                             \
    sv += __shfl_xor(sv, 32);                                             \
    float rv = __builtin_amdgcn_rcpf(sv);                                 \
    *(f32x4*)(SD + wbase + col * 64 + (TS) * 16 + g4)        = D * r1;    \
    *(f32x4*)(SD + wbase + col * 64 + (TS) * 16 + g4 + 1024) = pg * rv;   \
    FDST = sv;                                                            \
    _Pragma("unroll")                                                     \
    for (int ee = 0; ee < 4; ++ee) {                                      \
        h16 hh = (h16)pg[ee];                                             \
        bhi[ee] = hh;                                                     \
        blo[ee] = (h16)(pg[ee] - (float)hh);                              \
    }                                                                     \
    r1 = rv;                                                              \
} while (0)

    // ---- warm-up: 16 steps, no stores ----
    #pragma unroll 1
    for (int b = 0; b < WARMUP_W / 4; ++b) {
        float4 nn = yld(tb + 8);
        FSTEPW(c4.x);
        FSTEPW(c4.y);
        FSTEPW(c4.z);
        FSTEPW(c4.w);
        c4 = n1; n1 = nn; tb += 4;
    }

    // ---- main: 32 steps; stage 4-step tiles, flush as full-line stores ----
    f32x4 f4;
    #pragma unroll 1
    for (int b = 0; b < CHUNK_L / 4; ++b) {
        float4 nn = yld(tb + 8);
        FSTEPS(c4.x, 0, f4.x);
        FSTEPS(c4.y, 1, f4.y);
        FSTEPS(c4.z, 2, f4.z);
        FSTEPS(c4.w, 3, f4.w);
        if (lane < 16) *(f32x4*)(SD + ftb + col * 32 + b * 4) = f4;

        // flush: 4 store instrs per array, each = 4 x 256B full-line segments
        #pragma unroll
        for (int i = 0; i < 4; ++i) {
            const int cc = cbase + i * 4 + (lane >> 4);
            const int li = wbase + (i * 4 + (lane >> 4)) * 64 + (lane & 15) * 4;
            f32x4 vu = *(f32x4*)(SD + li);
            f32x4 vn = *(f32x4*)(SD + li + 1024);
            if (cc < nchunks) {
                float* dst = out + (size_t)cc * 512 + b * 64 + (lane & 15) * 4;
                *(f32x4*)dst        = vu;
                *(f32x4*)(dst + TN) = vn;
            }
        }
        c4 = n1; n1 = nn; tb += 4;
    }

    // ---- ft flush: 2KB contiguous per wave (full lines) ----
    {
        const int cc0 = cbase + (lane >> 2);
        if (cc0 < nchunks) {
            f32x4 a  = *(f32x4*)(SD + ftb + lane * 8);
            f32x4 bq = *(f32x4*)(SD + ftb + lane * 8 + 4);
            float* dst = out + 2 * (size_t)TN + (size_t)cbase * 32 + lane * 8;
            *(f32x4*)dst       = a;
            *(f32x4*)(dst + 4) = bq;
        }
    }
#undef FSTEPW
#undef FSTEPS
}

extern "C" void kernel_launch(void* const* d_in, const int* in_sizes, int n_in,
                              void* d_out, int out_size, void* d_ws, size_t ws_size,
                              hipStream_t stream) {
    const float* y      = (const float*)d_in[0];
    const float* logits = (const float*)d_in[1];
    const float* mu     = (const float*)d_in[2];
    const float* ls     = (const float*)d_in[3];
    float* out = (float*)d_out;
    const int T = in_sizes[0];                 // 500000 = 32 * 15625 (exact)

    const int nchunks = (T + CHUNK_L - 1) / CHUNK_L;
    const int nwaves  = (nchunks + 15) / 16;
    const int blocks  = (nwaves + 3) / 4;
    hmm_filter_kernel<<<blocks, 256, 0, stream>>>(y, logits, mu, ls, out,
                                                  T, nchunks);
}

// Round 7
// 89.037 us; speedup vs baseline: 1.0584x; 1.0584x over previous
//
#include <hip/hip_runtime.h>

// MFMA-batched overlapped-chunk HMM forward filter.
// R12: occupancy experiment. R11 (LDS-staged full-line stores) REGRESSED
// (kernel 18.8->23.4us) -> store-granularity theory refuted, staging removed.
// R9's geometry was 245 blocks = 0.96 waves/SIMD: zero TLP, all latencies
// (MFMA hazards, shfl DS path, exp2, y-miss, store backpressure) exposed.
// This round: CHUNK_L 32->16 at IDENTICAL arithmetic: per-wave serial work
// 48->32 steps, waves x2 (1954, ~1.9/SIMD, 489 blocks). Disambiguation:
//   latency/occupancy-bound -> total ~80-84us (kernel ~9-13)
//   write-BW-bound          -> total ~90 (kernel unchanged ~19)
//   issue-bound             -> total ~92-97 (1.33x steps)
#define CHUNK_L 16
#define WARMUP_W 16

typedef _Float16 h16;
typedef _Float16 h16x4 __attribute__((ext_vector_type(4)));
typedef float f32x4 __attribute__((ext_vector_type(4)));

static __device__ __forceinline__ f32x4 mfma16(h16x4 a, h16x4 b, f32x4 c) {
#if __has_builtin(__builtin_amdgcn_mfma_f32_16x16x16f16)
    return __builtin_amdgcn_mfma_f32_16x16x16f16(a, b, c, 0, 0, 0);
#else
    f32x4 d;
    asm volatile("v_mfma_f32_16x16x16_f16 %0, %1, %2, %3\n\ts_nop 7\n\ts_nop 7"
                 : "=v"(d) : "v"(a), "v"(b), "v"(c));
    return d;
#endif
}

__global__ __launch_bounds__(256, 4) void hmm_filter_kernel(
    const float* __restrict__ y,
    const float* __restrict__ logits,
    const float* __restrict__ mu,
    const float* __restrict__ log_sigma,
    float* __restrict__ out,
    int T, int nchunks)
{
    __shared__ float Plds[256];
    __shared__ float Ba[256];
    __shared__ float Bb[256];

    const int tid = (int)threadIdx.x;
    const int j   = tid & 15;     // column (preamble)
    const int gr  = tid >> 4;     // row (preamble)

    // ---- P = softmax(logits, axis=-1) ----
    float l = logits[tid];
    float m = l;
    #pragma unroll
    for (int s = 1; s < 16; s <<= 1) m = fmaxf(m, __shfl_xor(m, s, 16));
    float e = __expf(l - m);
    float rs = e;
    #pragma unroll
    for (int s = 1; s < 16; s <<= 1) rs += __shfl_xor(rs, s, 16);
    float Pv = e / rs;
    Plds[tid] = Pv;
    Ba[tid]   = Pv;
    __syncthreads();

    // ---- stationary pi: P^(2^10) via renormalized squaring (cold) ----
    float* cur = Ba;
    float* nxt = Bb;
    for (int itq = 0; itq < 10; ++itq) {
        float acc = 0.f;
        #pragma unroll
        for (int k = 0; k < 16; ++k)
            acc += cur[gr * 16 + k] * cur[k * 16 + j];
        float rsum = acc;
        #pragma unroll
        for (int s = 1; s < 16; s <<= 1) rsum += __shfl_xor(rsum, s, 16);
        nxt[tid] = acc / rsum;
        __syncthreads();
        float* tmp = cur; cur = nxt; nxt = tmp;
    }
    // no barriers below this point (early return is safe)

    // ---- lane / wave geometry ----
    const int lane = tid & 63;
    const int col  = lane & 15;          // chunk column  (n)
    const int i0   = (lane >> 4) << 2;   // first of this lane's 4 states
    const int wv   = ((int)blockIdx.x << 2) + (tid >> 6);
    const int cbase = wv << 4;

    // A = P^T fragments, hi/lo f16 split.  A[m][k]: m=lane%16, k=i0+ee.
    // A[m][k] = P[k][m] = Plds[(i0+ee)*16 + col].
    h16x4 Ahi, Alo;
    #pragma unroll
    for (int ee = 0; ee < 4; ++ee) {
        float a = Plds[(i0 + ee) * 16 + col];
        h16 hi = (h16)a;
        Ahi[ee] = hi;
        Alo[ee] = (h16)(a - (float)hi);
    }

    // initial p~ = pi  (B[k][n]: k=i0+ee, same for every chunk column)
    h16x4 bhi, blo;
    #pragma unroll
    for (int ee = 0; ee < 4; ++ee) {
        float pv = cur[i0 + ee];
        h16 hi = (h16)pv;
        bhi[ee] = hi;
        blo[ee] = (h16)(pv - (float)hi);
    }

    // emission constants for this lane's 4 states
    float isv[4], nmv[4], lcv[4];
    #pragma unroll
    for (int ee = 0; ee < 4; ++ee) {
        int st = i0 + ee;
        float is = __expf(-log_sigma[st]);
        isv[ee] = is;
        nmv[ee] = -mu[st] * is;
        lcv[ee] = __log2f(0.3989422804014327f * is);
    }
    const float K2 = -0.7213475204444817f;   // -0.5*log2(e)

    if (cbase >= nchunks) return;

    const int chunk = cbase + col;
    const bool live = chunk < nchunks;       // ghost chunks: no stores
    const bool isC0 = (chunk == 0);          // warm with g==1 (pi stationary)
    const int Tm4 = T - 4;
    const int TN  = T << 4;

    int tb = chunk * CHUNK_L - WARMUP_W;     // t of current y 4-block

    auto yld = [&](int t) -> float4 {
        int tc = t < 0 ? 0 : (t > Tm4 ? Tm4 : t);
        return *(const float4*)(y + tc);
    };

    float4 c4 = yld(tb);
    float4 n1 = yld(tb + 4);

    float r1 = 1.0f;   // rcp(rowsum of previous step) = 1/c_{t-1}

// One filter step. Chain: 3 MFMA -> *eg -> f16 split. rowsum/rcp, outputs
// hang off the chain. alpha = r1 (1-step lag) keeps carried scale = f_t.
#define FSTEP(YT, WARM, DOST, UTP, UNP, FDST)  do {                       \
    f32x4 D = {0.f, 0.f, 0.f, 0.f};                                       \
    D = mfma16(Ahi, bhi, D);                                              \
    D = mfma16(Alo, bhi, D);                                              \
    D = mfma16(Ahi, blo, D);                                              \
    f32x4 eg;                                                             \
    _Pragma("unroll")                                                     \
    for (int ee = 0; ee < 4; ++ee) {                                      \
        float z  = fmaf((YT), isv[ee], nmv[ee]);                          \
        float gg = __builtin_amdgcn_exp2f(fmaf(z * z, K2, lcv[ee]));      \
        if (WARM) gg = isC0 ? 1.0f : gg;                                  \
        eg[ee] = gg * r1;                                                 \
    }                                                                     \
    f32x4 pg = D * eg;                                                    \
    float sv = (pg.x + pg.y) + (pg.z + pg.w);                             \
    sv += __shfl_xor(sv, 16);                                             \
    sv += __shfl_xor(sv, 32);                                             \
    float rv = __builtin_amdgcn_rcpf(sv);                                 \
    if ((DOST) && live) {                                                 \
        f32x4 ut = D * r1;                                                \
        f32x4 un = pg * rv;                                               \
        *(f32x4*)(UTP) = ut;                                              \
        *(f32x4*)(UNP) = un;                                              \
    }                                                                     \
    if (DOST) { FDST = sv; }                                              \
    _Pragma("unroll")                                                     \
    for (int ee = 0; ee < 4; ++ee) {                                      \
        h16 hh = (h16)pg[ee];                                             \
        bhi[ee] = hh;                                                     \
        blo[ee] = (h16)(pg[ee] - (float)hh);                              \
    }                                                                     \
    r1 = rv;                                                              \
} while (0)

    // ---- warm-up: 16 steps, no stores ----
    float fdummy;
    #pragma unroll 1
    for (int b = 0; b < WARMUP_W / 4; ++b) {
        float4 nn = yld(tb + 8);
        FSTEP(c4.x, true, false, out, out, fdummy);
        FSTEP(c4.y, true, false, out, out, fdummy);
        FSTEP(c4.z, true, false, out, out, fdummy);
        FSTEP(c4.w, true, false, out, out, fdummy);
        c4 = n1; n1 = nn; tb += 4;
    }
    (void)fdummy;

    // ---- main: CHUNK_L steps with stores ----
    float* pU = out + ((chunk * CHUNK_L) << 4) + i0;   // ut  [t][state]
    float* pN = pU + TN;                               // u_norm
    float* pF = out + 2 * TN + chunk * CHUNK_L;        // ft (lanes<16)
    f32x4 f4;

    #pragma unroll 1
    for (int b = 0; b < CHUNK_L / 4; ++b) {
        float4 nn = yld(tb + 8);
        FSTEP(c4.x, false, true, pU,      pN,      f4.x);
        FSTEP(c4.y, false, true, pU + 16, pN + 16, f4.y);
        FSTEP(c4.z, false, true, pU + 32, pN + 32, f4.z);
        FSTEP(c4.w, false, true, pU + 48, pN + 48, f4.w);
        if (lane < 16 && live) *(f32x4*)(pF) = f4;
        pU += 64; pN += 64; pF += 4;
        c4 = n1; n1 = nn; tb += 4;
    }
#undef FSTEP
}

extern "C" void kernel_launch(void* const* d_in, const int* in_sizes, int n_in,
                              void* d_out, int out_size, void* d_ws, size_t ws_size,
                              hipStream_t stream) {
    const float* y      = (const float*)d_in[0];
    const float* logits = (const float*)d_in[1];
    const float* mu     = (const float*)d_in[2];
    const float* ls     = (const float*)d_in[3];
    float* out = (float*)d_out;
    const int T = in_sizes[0];                 // 500000 = 16 * 31250 (exact)

    const int nchunks = (T + CHUNK_L - 1) / CHUNK_L;
    const int nwaves  = (nchunks + 15) / 16;
    const int blocks  = (nwaves + 3) / 4;
    hmm_filter_kernel<<<blocks, 256, 0, stream>>>(y, logits, mu, ls, out,
                                                  T, nchunks);
}